// Round 1
// baseline (332.666 us; speedup 1.0000x reference)
//
#include <hip/hip_runtime.h>
#include <math.h>

// EdgeBiasAttention: B=2, N=20000, C=64, E=640000, H=16
// Strategy: per-edge bias MLP -> CSR by dst -> one wave per (node,batch),
// lane==channel, online softmax over incoming edges.

#define EB_B 2
#define EB_C 64
#define EB_H 16

__global__ void eb_bias_kernel(const float* __restrict__ efeat,
                               const float* __restrict__ W1,
                               const float* __restrict__ b1,
                               const float* __restrict__ W2,
                               const float* __restrict__ b2,
                               float* __restrict__ bias, int E) {
    int e = blockIdx.x * blockDim.x + threadIdx.x;
    if (e >= E) return;
    float ef0 = efeat[2 * e];
    float ef1 = efeat[2 * e + 1];
    float acc = b2[0];
#pragma unroll
    for (int h = 0; h < EB_H; ++h) {
        float a = fmaf(ef0, W1[h], fmaf(ef1, W1[EB_H + h], b1[h]));
        a = fmaxf(a, 0.0f);
        acc = fmaf(a, W2[h], acc);
    }
    bias[e] = acc;
}

__global__ void eb_count_kernel(const int* __restrict__ dst,
                                int* __restrict__ cnt, int E) {
    int e = blockIdx.x * blockDim.x + threadIdx.x;
    if (e < E) atomicAdd(&cnt[dst[e]], 1);
}

// Single-block exclusive scan over N counts -> offsets[N+1]; also copies to cursor.
__global__ void eb_scan_kernel(const int* __restrict__ cnt,
                               int* __restrict__ offsets,
                               int* __restrict__ cursor, int N, int E) {
    __shared__ int lds[1024];
    __shared__ int s_carry;
    int tid = threadIdx.x;
    if (tid == 0) s_carry = 0;
    __syncthreads();
    int nchunk = (N + 1023) >> 10;
    for (int c = 0; c < nchunk; ++c) {
        int i = (c << 10) + tid;
        int v = (i < N) ? cnt[i] : 0;
        lds[tid] = v;
        __syncthreads();
        for (int off = 1; off < 1024; off <<= 1) {
            int t = (tid >= off) ? lds[tid - off] : 0;
            __syncthreads();
            lds[tid] += t;
            __syncthreads();
        }
        int carry = s_carry;
        int excl = carry + lds[tid] - v;
        if (i < N) { offsets[i] = excl; cursor[i] = excl; }
        __syncthreads();
        if (tid == 1023) s_carry = carry + lds[1023];
        __syncthreads();
    }
    if (tid == 0) offsets[N] = E;
}

__global__ void eb_fill_kernel(const int* __restrict__ dst,
                               int* __restrict__ cursor,
                               int* __restrict__ elist, int E) {
    int e = blockIdx.x * blockDim.x + threadIdx.x;
    if (e < E) {
        int pos = atomicAdd(&cursor[dst[e]], 1);
        elist[pos] = e;
    }
}

// One wave per (node, batch). lane == channel (C=64).
__global__ __launch_bounds__(256) void eb_attn_kernel(
    const float* __restrict__ Q, const float* __restrict__ K,
    const float* __restrict__ V, const float* __restrict__ bias,
    const int* __restrict__ src, const int* __restrict__ offsets,
    const int* __restrict__ elist, float* __restrict__ out, int N) {
    int wave = threadIdx.x >> 6;
    int lane = threadIdx.x & 63;
    int task = blockIdx.x * 4 + wave;
    if (task >= N * EB_B) return;
    int n = task >> 1;       // node
    int b = task & 1;        // batch
    const int bstride = N * EB_C;
    const float* Qb = Q + (size_t)b * bstride;
    const float* Kb = K + (size_t)b * bstride;
    const float* Vb = V + (size_t)b * bstride;

    float q = Qb[n * EB_C + lane];
    int start = offsets[n];
    int end = offsets[n + 1];

    float m = -INFINITY, s = 0.0f, acc = 0.0f;
    for (int ei = start; ei < end; ++ei) {
        int e = elist[ei];
        int sv = src[e];
        float k = Kb[sv * EB_C + lane];
        float p = q * k;
#pragma unroll
        for (int mask = 32; mask >= 1; mask >>= 1)
            p += __shfl_xor(p, mask, 64);
        float l = p + bias[e];
        float mn = fmaxf(m, l);
        float sc = __expf(m - mn);   // 0 on first iter (m = -inf)
        float w  = __expf(l - mn);
        float v  = Vb[sv * EB_C + lane];
        s   = fmaf(s, sc, w);
        acc = fmaf(acc, sc, w * v);
        m = mn;
    }
    out[(size_t)b * bstride + n * EB_C + lane] = (end > start) ? acc / s : 0.0f;
}

extern "C" void kernel_launch(void* const* d_in, const int* in_sizes, int n_in,
                              void* d_out, int out_size, void* d_ws, size_t ws_size,
                              hipStream_t stream) {
    const float* Q     = (const float*)d_in[0];
    const float* K     = (const float*)d_in[1];
    const float* V     = (const float*)d_in[2];
    const float* efeat = (const float*)d_in[3];
    const float* W1    = (const float*)d_in[4];
    const float* b1    = (const float*)d_in[5];
    const float* W2    = (const float*)d_in[6];
    const float* b2    = (const float*)d_in[7];
    const int*   src   = (const int*)d_in[8];
    const int*   dst   = (const int*)d_in[9];
    float* out = (float*)d_out;

    const int E = in_sizes[8];
    const int N = in_sizes[0] / (EB_B * EB_C);

    // workspace layout (all 4-byte elements)
    float* bias   = (float*)d_ws;          // E
    int* offsets  = (int*)(bias + E);      // N+1
    int* cursor   = offsets + (N + 1);     // N
    int* cnt      = cursor + N;            // N
    int* elist    = cnt + N;               // E

    hipMemsetAsync(cnt, 0, (size_t)N * sizeof(int), stream);

    int tpb = 256;
    eb_bias_kernel<<<(E + tpb - 1) / tpb, tpb, 0, stream>>>(efeat, W1, b1, W2, b2, bias, E);
    eb_count_kernel<<<(E + tpb - 1) / tpb, tpb, 0, stream>>>(dst, cnt, E);
    eb_scan_kernel<<<1, 1024, 0, stream>>>(cnt, offsets, cursor, N, E);
    eb_fill_kernel<<<(E + tpb - 1) / tpb, tpb, 0, stream>>>(dst, cursor, elist, E);

    int tasks = N * EB_B;
    eb_attn_kernel<<<(tasks + 3) / 4, tpb, 0, stream>>>(Q, K, V, bias, src, offsets, elist, out, N);
}

// Round 2
// 199.559 us; speedup vs baseline: 1.6670x; 1.6670x over previous
//
#include <hip/hip_runtime.h>
#include <math.h>

// EdgeBiasAttention: B=2, N=20000, C=64, E=640000, H=16
// CSR by dst with PERMUTED src/bias (no elist indirection in hot loop),
// one wave per (node,batch), lane==channel, 4-edge-unrolled online softmax.

#define EB_B 2
#define EB_C 64
#define EB_H 16

__global__ void eb_count_kernel(const int* __restrict__ dst,
                                int* __restrict__ cnt, int E) {
    int e = blockIdx.x * blockDim.x + threadIdx.x;
    if (e < E) atomicAdd(&cnt[dst[e]], 1);
}

// Single-block scan via wave shuffles: offsets[N+1] (+ cursor copy).
__global__ void eb_scan_kernel(const int* __restrict__ cnt,
                               int* __restrict__ offsets,
                               int* __restrict__ cursor, int N, int E) {
    __shared__ int wsum[16];
    __shared__ int s_carry;
    int tid = threadIdx.x;
    int wv = tid >> 6, ln = tid & 63;
    if (tid == 0) s_carry = 0;
    __syncthreads();
    int nchunk = (N + 1023) >> 10;
    for (int c = 0; c < nchunk; ++c) {
        int i = (c << 10) + tid;
        int v = (i < N) ? cnt[i] : 0;
        int x = v;
#pragma unroll
        for (int off = 1; off < 64; off <<= 1) {
            int t = __shfl_up(x, off, 64);
            if (ln >= off) x += t;
        }
        if (ln == 63) wsum[wv] = x;
        __syncthreads();
        if (wv == 0 && ln < 16) {
            int y = wsum[ln];
#pragma unroll
            for (int off = 1; off < 16; off <<= 1) {
                int t = __shfl_up(y, off, 64);
                if (ln >= off) y += t;
            }
            wsum[ln] = y;
        }
        __syncthreads();
        int base = s_carry + (wv > 0 ? wsum[wv - 1] : 0);
        if (i < N) {
            int excl = base + x - v;
            offsets[i] = excl;
            cursor[i] = excl;
        }
        __syncthreads();
        if (tid == 1023) s_carry = base + x;
        __syncthreads();
    }
    if (tid == 0) offsets[N] = E;
}

// Fill permuted arrays AND compute the edge-bias MLP on the fly.
__global__ void eb_fill_kernel(const int* __restrict__ dst,
                               const int* __restrict__ src,
                               const float* __restrict__ efeat,
                               const float* __restrict__ W1,
                               const float* __restrict__ b1,
                               const float* __restrict__ W2,
                               const float* __restrict__ b2,
                               int* __restrict__ cursor,
                               int* __restrict__ src_perm,
                               float* __restrict__ bias_perm, int E) {
    int e = blockIdx.x * blockDim.x + threadIdx.x;
    if (e >= E) return;
    float ef0 = efeat[2 * e];
    float ef1 = efeat[2 * e + 1];
    float acc = b2[0];
#pragma unroll
    for (int h = 0; h < EB_H; ++h) {
        float a = fmaf(ef0, W1[h], fmaf(ef1, W1[EB_H + h], b1[h]));
        a = fmaxf(a, 0.0f);
        acc = fmaf(a, W2[h], acc);
    }
    int pos = atomicAdd(&cursor[dst[e]], 1);
    src_perm[pos] = src[e];
    bias_perm[pos] = acc;
}

// One wave per (node, batch). lane == channel (C=64). 4-edge unroll.
__global__ __launch_bounds__(256) void eb_attn_kernel(
    const float* __restrict__ Q, const float* __restrict__ K,
    const float* __restrict__ V,
    const int* __restrict__ src_perm, const float* __restrict__ bias_perm,
    const int* __restrict__ offsets, float* __restrict__ out, int N) {
    int wave = threadIdx.x >> 6;
    int lane = threadIdx.x & 63;
    int task = blockIdx.x * 4 + wave;
    if (task >= N * EB_B) return;
    int n = task >> 1;       // node
    int b = task & 1;        // batch
    const int bstride = N * EB_C;
    const float* Qb = Q + (size_t)b * bstride;
    const float* Kb = K + (size_t)b * bstride;
    const float* Vb = V + (size_t)b * bstride;

    float q = Qb[n * EB_C + lane];
    int start = offsets[n];
    int end = offsets[n + 1];

    float m = -INFINITY, s = 0.0f, acc = 0.0f;
    int ei = start;
    for (; ei + 4 <= end; ei += 4) {
        int s0 = src_perm[ei];
        int s1 = src_perm[ei + 1];
        int s2 = src_perm[ei + 2];
        int s3 = src_perm[ei + 3];
        float b0 = bias_perm[ei];
        float b1_ = bias_perm[ei + 1];
        float b2_ = bias_perm[ei + 2];
        float b3 = bias_perm[ei + 3];
        float k0 = Kb[s0 * EB_C + lane];
        float k1 = Kb[s1 * EB_C + lane];
        float k2 = Kb[s2 * EB_C + lane];
        float k3 = Kb[s3 * EB_C + lane];
        float v0 = Vb[s0 * EB_C + lane];
        float v1 = Vb[s1 * EB_C + lane];
        float v2 = Vb[s2 * EB_C + lane];
        float v3 = Vb[s3 * EB_C + lane];
        float p0 = q * k0, p1 = q * k1, p2 = q * k2, p3 = q * k3;
#pragma unroll
        for (int mask = 32; mask >= 1; mask >>= 1) {
            p0 += __shfl_xor(p0, mask, 64);
            p1 += __shfl_xor(p1, mask, 64);
            p2 += __shfl_xor(p2, mask, 64);
            p3 += __shfl_xor(p3, mask, 64);
        }
        float l0 = p0 + b0, l1 = p1 + b1_, l2 = p2 + b2_, l3 = p3 + b3;
        float mx = fmaxf(fmaxf(l0, l1), fmaxf(l2, l3));
        float mn = fmaxf(m, mx);
        float sc = __expf(m - mn);           // 0 on first group
        float w0 = __expf(l0 - mn);
        float w1 = __expf(l1 - mn);
        float w2 = __expf(l2 - mn);
        float w3 = __expf(l3 - mn);
        s = fmaf(s, sc, (w0 + w1) + (w2 + w3));
        acc = fmaf(acc, sc,
              fmaf(w0, v0, fmaf(w1, v1, fmaf(w2, v2, w3 * v3))));
        m = mn;
    }
    for (; ei < end; ++ei) {
        int sv = src_perm[ei];
        float k = Kb[sv * EB_C + lane];
        float v = Vb[sv * EB_C + lane];
        float p = q * k;
#pragma unroll
        for (int mask = 32; mask >= 1; mask >>= 1)
            p += __shfl_xor(p, mask, 64);
        float l = p + bias_perm[ei];
        float mn = fmaxf(m, l);
        float sc = __expf(m - mn);
        float w = __expf(l - mn);
        s = fmaf(s, sc, w);
        acc = fmaf(acc, sc, w * v);
        m = mn;
    }
    out[(size_t)b * bstride + n * EB_C + lane] = (end > start) ? acc / s : 0.0f;
}

extern "C" void kernel_launch(void* const* d_in, const int* in_sizes, int n_in,
                              void* d_out, int out_size, void* d_ws, size_t ws_size,
                              hipStream_t stream) {
    const float* Q     = (const float*)d_in[0];
    const float* K     = (const float*)d_in[1];
    const float* V     = (const float*)d_in[2];
    const float* efeat = (const float*)d_in[3];
    const float* W1    = (const float*)d_in[4];
    const float* b1    = (const float*)d_in[5];
    const float* W2    = (const float*)d_in[6];
    const float* b2    = (const float*)d_in[7];
    const int*   src   = (const int*)d_in[8];
    const int*   dst   = (const int*)d_in[9];
    float* out = (float*)d_out;

    const int E = in_sizes[8];
    const int N = in_sizes[0] / (EB_B * EB_C);

    // workspace layout (4-byte elements): offsets[N+1] cursor[N] cnt[N]
    // src_perm[E] bias_perm[E]
    int* offsets    = (int*)d_ws;
    int* cursor     = offsets + (N + 1);
    int* cnt        = cursor + N;
    int* src_perm   = cnt + N;
    float* bias_perm = (float*)(src_perm + E);

    hipMemsetAsync(cnt, 0, (size_t)N * sizeof(int), stream);

    int tpb = 256;
    eb_count_kernel<<<(E + tpb - 1) / tpb, tpb, 0, stream>>>(dst, cnt, E);
    eb_scan_kernel<<<1, 1024, 0, stream>>>(cnt, offsets, cursor, N, E);
    eb_fill_kernel<<<(E + tpb - 1) / tpb, tpb, 0, stream>>>(
        dst, src, efeat, W1, b1, W2, b2, cursor, src_perm, bias_perm, E);

    int tasks = N * EB_B;
    eb_attn_kernel<<<(tasks + 3) / 4, tpb, 0, stream>>>(
        Q, K, V, src_perm, bias_perm, offsets, out, N);
}

// Round 3
// 156.735 us; speedup vs baseline: 2.1225x; 1.2732x over previous
//
#include <hip/hip_runtime.h>
#include <math.h>

// EdgeBiasAttention: B=2, N=20000, C=64, E=640000, H=16
// CSR by dst; fused (src,bias) int2 stream; one wave per (node,batch);
// 4 groups of 16 lanes, each group owns every 4th edge with its own
// online-softmax state; states merged via xor-16/32 shuffles at the end.

#define EB_B 2
#define EB_C 64
#define EB_H 16

// Pass 1: histogram dst AND remember each edge's slot within its segment.
__global__ void eb_count_kernel(const int* __restrict__ dst,
                                int* __restrict__ cnt,
                                int* __restrict__ slot, int E) {
    int e = blockIdx.x * blockDim.x + threadIdx.x;
    if (e < E) slot[e] = atomicAdd(&cnt[dst[e]], 1);
}

// Single-block shuffle scan: offsets[N+1].
__global__ void eb_scan_kernel(const int* __restrict__ cnt,
                               int* __restrict__ offsets, int N, int E) {
    __shared__ int wsum[16];
    __shared__ int s_carry;
    int tid = threadIdx.x;
    int wv = tid >> 6, ln = tid & 63;
    if (tid == 0) s_carry = 0;
    __syncthreads();
    int nchunk = (N + 1023) >> 10;
    for (int c = 0; c < nchunk; ++c) {
        int i = (c << 10) + tid;
        int v = (i < N) ? cnt[i] : 0;
        int x = v;
#pragma unroll
        for (int off = 1; off < 64; off <<= 1) {
            int t = __shfl_up(x, off, 64);
            if (ln >= off) x += t;
        }
        if (ln == 63) wsum[wv] = x;
        __syncthreads();
        if (wv == 0 && ln < 16) {
            int y = wsum[ln];
#pragma unroll
            for (int off = 1; off < 16; off <<= 1) {
                int t = __shfl_up(y, off, 64);
                if (ln >= off) y += t;
            }
            wsum[ln] = y;
        }
        __syncthreads();
        int base = s_carry + (wv > 0 ? wsum[wv - 1] : 0);
        if (i < N) offsets[i] = base + x - v;
        __syncthreads();
        if (tid == 1023) s_carry = base + x;
        __syncthreads();
    }
    if (tid == 0) offsets[N] = E;
}

// Pass 2: atomic-free scatter of fused (src, bias) records; MLP inline.
__global__ void eb_fill_kernel(const int* __restrict__ dst,
                               const int* __restrict__ src,
                               const int* __restrict__ slot,
                               const int* __restrict__ offsets,
                               const float* __restrict__ efeat,
                               const float* __restrict__ W1,
                               const float* __restrict__ b1,
                               const float* __restrict__ W2,
                               const float* __restrict__ b2,
                               int2* __restrict__ ep, int E) {
    int e = blockIdx.x * blockDim.x + threadIdx.x;
    if (e >= E) return;
    float ef0 = efeat[2 * e];
    float ef1 = efeat[2 * e + 1];
    float acc = b2[0];
#pragma unroll
    for (int h = 0; h < EB_H; ++h) {
        float a = fmaf(ef0, W1[h], fmaf(ef1, W1[EB_H + h], b1[h]));
        a = fmaxf(a, 0.0f);
        acc = fmaf(a, W2[h], acc);
    }
    int pos = offsets[dst[e]] + slot[e];
    ep[pos] = make_int2(src[e], __float_as_int(acc));
}

// One wave per (node, batch). 4 groups x 16 lanes; lane&15 owns a
// float4 channel quad; group g takes edges start+g, start+g+4, ...
__global__ __launch_bounds__(256) void eb_attn_kernel(
    const float4* __restrict__ Q4, const float4* __restrict__ K4,
    const float4* __restrict__ V4,
    const int2* __restrict__ ep, const int* __restrict__ offsets,
    float4* __restrict__ out4, int N) {
    int wave = threadIdx.x >> 6;
    int lane = threadIdx.x & 63;
    int task = blockIdx.x * 4 + wave;
    if (task >= N * EB_B) return;
    int n = task >> 1;
    int b = task & 1;
    int g = lane >> 4;
    int cl = lane & 15;
    const size_t brow = (size_t)N * 16;   // float4s per batch
    const float4* Qb = Q4 + (size_t)b * brow;
    const float4* Kb = K4 + (size_t)b * brow;
    const float4* Vb = V4 + (size_t)b * brow;

    float4 q = Qb[(size_t)n * 16 + cl];
    int start = offsets[n];
    int end = offsets[n + 1];
    int nit = (end - start + 3) >> 2;

    float m = -1e30f, s = 0.0f;
    float ax = 0.0f, ay = 0.0f, az = 0.0f, aw = 0.0f;

    for (int it = 0; it < nit; ++it) {
        int ei = start + it * 4 + g;
        bool valid = ei < end;
        int2 md = ep[valid ? ei : start];
        int sv = md.x;
        float4 k = Kb[(size_t)sv * 16 + cl];
        float4 v = Vb[(size_t)sv * 16 + cl];
        float p = fmaf(q.x, k.x, fmaf(q.y, k.y, fmaf(q.z, k.z, q.w * k.w)));
        p += __shfl_xor(p, 1);
        p += __shfl_xor(p, 2);
        p += __shfl_xor(p, 4);
        p += __shfl_xor(p, 8);
        float l = valid ? p + __int_as_float(md.y) : -INFINITY;
        float mn = fmaxf(m, l);
        float sc = __expf(m - mn);   // finite: m >= -1e30, mn >= m
        float w  = __expf(l - mn);   // 0 for invalid edges
        s  = fmaf(s, sc, w);
        ax = fmaf(ax, sc, w * v.x);
        ay = fmaf(ay, sc, w * v.y);
        az = fmaf(az, sc, w * v.z);
        aw = fmaf(aw, sc, w * v.w);
        m = mn;
    }

    // merge the 4 group states
    float m1 = fmaxf(m, __shfl_xor(m, 16));
    float mA = fmaxf(m1, __shfl_xor(m1, 32));
    float scale = __expf(m - mA);
    s *= scale; ax *= scale; ay *= scale; az *= scale; aw *= scale;
    s  += __shfl_xor(s, 16);  s  += __shfl_xor(s, 32);
    ax += __shfl_xor(ax, 16); ax += __shfl_xor(ax, 32);
    ay += __shfl_xor(ay, 16); ay += __shfl_xor(ay, 32);
    az += __shfl_xor(az, 16); az += __shfl_xor(az, 32);
    aw += __shfl_xor(aw, 16); aw += __shfl_xor(aw, 32);

    if (lane < 16) {
        float inv = (end > start) ? 1.0f / s : 0.0f;
        float4 o;
        o.x = ax * inv; o.y = ay * inv; o.z = az * inv; o.w = aw * inv;
        out4[(size_t)b * brow + (size_t)n * 16 + cl] = o;
    }
}

extern "C" void kernel_launch(void* const* d_in, const int* in_sizes, int n_in,
                              void* d_out, int out_size, void* d_ws, size_t ws_size,
                              hipStream_t stream) {
    const float* Q     = (const float*)d_in[0];
    const float* K     = (const float*)d_in[1];
    const float* V     = (const float*)d_in[2];
    const float* efeat = (const float*)d_in[3];
    const float* W1    = (const float*)d_in[4];
    const float* b1    = (const float*)d_in[5];
    const float* W2    = (const float*)d_in[6];
    const float* b2    = (const float*)d_in[7];
    const int*   src   = (const int*)d_in[8];
    const int*   dst   = (const int*)d_in[9];
    float* out = (float*)d_out;

    const int E = in_sizes[8];
    const int N = in_sizes[0] / (EB_B * EB_C);

    // ws layout (ints): offsets[N+1] cnt[N] slot[E] ep[2*E]
    int* offsets = (int*)d_ws;
    int* cnt     = offsets + (N + 1);
    int* slot    = cnt + N;
    int2* ep     = (int2*)(slot + E);

    hipMemsetAsync(cnt, 0, (size_t)N * sizeof(int), stream);

    int tpb = 256;
    eb_count_kernel<<<(E + tpb - 1) / tpb, tpb, 0, stream>>>(dst, cnt, slot, E);
    eb_scan_kernel<<<1, 1024, 0, stream>>>(cnt, offsets, N, E);
    eb_fill_kernel<<<(E + tpb - 1) / tpb, tpb, 0, stream>>>(
        dst, src, slot, offsets, efeat, W1, b1, W2, b2, ep, E);

    int tasks = N * EB_B;
    eb_attn_kernel<<<(tasks + 3) / 4, tpb, 0, stream>>>(
        (const float4*)Q, (const float4*)K, (const float4*)V,
        ep, offsets, (float4*)out, N);
}

// Round 4
// 141.504 us; speedup vs baseline: 2.3509x; 1.1076x over previous
//
#include <hip/hip_runtime.h>
#include <math.h>

// EdgeBiasAttention: B=2, N=20000, C=64, E=640000, H=16
// CSR by dst (atomic-slot + hierarchical 3-kernel scan); fused (src,bias)
// int2 stream; attn: one wave per (node,batch), 4 groups x 16 lanes,
// 2 edges per group per iteration (8 in flight), online softmax.

#define EB_B 2
#define EB_C 64
#define EB_H 16

// Pass 1: histogram dst AND remember each edge's slot within its segment.
__global__ void eb_count_kernel(const int* __restrict__ dst,
                                int* __restrict__ cnt,
                                int* __restrict__ slot, int E) {
    int e = blockIdx.x * blockDim.x + threadIdx.x;
    if (e < E) slot[e] = atomicAdd(&cnt[dst[e]], 1);
}

// Scan stage 1: per-block (1024) local exclusive scan + block sums.
__global__ __launch_bounds__(1024) void eb_scan1(const int* __restrict__ cnt,
                                                 int* __restrict__ offsets,
                                                 int* __restrict__ bsum, int N) {
    __shared__ int wsum[16];
    int tid = threadIdx.x;
    int wv = tid >> 6, ln = tid & 63;
    int i = blockIdx.x * 1024 + tid;
    int v = (i < N) ? cnt[i] : 0;
    int x = v;
#pragma unroll
    for (int off = 1; off < 64; off <<= 1) {
        int t = __shfl_up(x, off, 64);
        if (ln >= off) x += t;
    }
    if (ln == 63) wsum[wv] = x;
    __syncthreads();
    if (wv == 0 && ln < 16) {
        int y = wsum[ln];
#pragma unroll
        for (int off = 1; off < 16; off <<= 1) {
            int t = __shfl_up(y, off, 64);
            if (ln >= off) y += t;
        }
        wsum[ln] = y;
    }
    __syncthreads();
    int base = (wv > 0 ? wsum[wv - 1] : 0);
    if (i < N) offsets[i] = base + x - v;      // block-local exclusive
    if (tid == 1023) bsum[blockIdx.x] = base + x;  // block total
}

// Scan stage 2: one wave scans the (<=64) block sums -> exclusive bases.
__global__ void eb_scan2(int* __restrict__ bsum, int NB) {
    int ln = threadIdx.x;
    int v = (ln < NB) ? bsum[ln] : 0;
    int x = v;
#pragma unroll
    for (int off = 1; off < 64; off <<= 1) {
        int t = __shfl_up(x, off, 64);
        if (ln >= off) x += t;
    }
    if (ln < NB) bsum[ln] = x - v;
}

// Scan stage 3: add block base; write the sentinel offsets[N] = E.
__global__ __launch_bounds__(1024) void eb_scan3(int* __restrict__ offsets,
                                                 const int* __restrict__ bsum,
                                                 int N, int E) {
    int i = blockIdx.x * 1024 + threadIdx.x;
    if (i < N) offsets[i] += bsum[blockIdx.x];
    else if (i == N) offsets[N] = E;
}

// Pass 2: atomic-free scatter of fused (src, bias) records; MLP inline.
__global__ void eb_fill_kernel(const int* __restrict__ dst,
                               const int* __restrict__ src,
                               const int* __restrict__ slot,
                               const int* __restrict__ offsets,
                               const float* __restrict__ efeat,
                               const float* __restrict__ W1,
                               const float* __restrict__ b1,
                               const float* __restrict__ W2,
                               const float* __restrict__ b2,
                               int2* __restrict__ ep, int E) {
    int e = blockIdx.x * blockDim.x + threadIdx.x;
    if (e >= E) return;
    float ef0 = efeat[2 * e];
    float ef1 = efeat[2 * e + 1];
    float acc = b2[0];
#pragma unroll
    for (int h = 0; h < EB_H; ++h) {
        float a = fmaf(ef0, W1[h], fmaf(ef1, W1[EB_H + h], b1[h]));
        a = fmaxf(a, 0.0f);
        acc = fmaf(a, W2[h], acc);
    }
    int pos = offsets[dst[e]] + slot[e];
    ep[pos] = make_int2(src[e], __float_as_int(acc));
}

// One wave per (node, batch). 4 groups x 16 lanes; group g takes edges
// start + it*8 + g and start + it*8 + g + 4 (2 per iteration, 8 in flight).
__global__ __launch_bounds__(256) void eb_attn_kernel(
    const float4* __restrict__ Q4, const float4* __restrict__ K4,
    const float4* __restrict__ V4,
    const int2* __restrict__ ep, const int* __restrict__ offsets,
    float4* __restrict__ out4, int N) {
    int wave = threadIdx.x >> 6;
    int lane = threadIdx.x & 63;
    int task = blockIdx.x * 4 + wave;
    if (task >= N * EB_B) return;
    int n = task >> 1;
    int b = task & 1;
    int g = lane >> 4;
    int cl = lane & 15;
    const size_t brow = (size_t)N * 16;   // float4s per batch
    const float4* Qb = Q4 + (size_t)b * brow;
    const float4* Kb = K4 + (size_t)b * brow;
    const float4* Vb = V4 + (size_t)b * brow;

    float4 q = Qb[(size_t)n * 16 + cl];
    int start = offsets[n];
    int end = offsets[n + 1];
    int nit = (end - start + 7) >> 3;

    float m = -1e30f, s = 0.0f;
    float ax = 0.0f, ay = 0.0f, az = 0.0f, aw = 0.0f;

    for (int it = 0; it < nit; ++it) {
        int e0 = start + it * 8 + g;
        int e1 = e0 + 4;
        bool v0 = e0 < end;
        bool v1 = e1 < end;
        int2 md0 = ep[v0 ? e0 : start];
        int2 md1 = ep[v1 ? e1 : start];
        int s0 = md0.x, s1 = md1.x;
        float4 k0 = Kb[(size_t)s0 * 16 + cl];
        float4 k1 = Kb[(size_t)s1 * 16 + cl];
        float4 vv0 = Vb[(size_t)s0 * 16 + cl];
        float4 vv1 = Vb[(size_t)s1 * 16 + cl];
        float p0 = fmaf(q.x, k0.x, fmaf(q.y, k0.y, fmaf(q.z, k0.z, q.w * k0.w)));
        float p1 = fmaf(q.x, k1.x, fmaf(q.y, k1.y, fmaf(q.z, k1.z, q.w * k1.w)));
        p0 += __shfl_xor(p0, 1);  p1 += __shfl_xor(p1, 1);
        p0 += __shfl_xor(p0, 2);  p1 += __shfl_xor(p1, 2);
        p0 += __shfl_xor(p0, 4);  p1 += __shfl_xor(p1, 4);
        p0 += __shfl_xor(p0, 8);  p1 += __shfl_xor(p1, 8);
        float l0 = v0 ? p0 + __int_as_float(md0.y) : -INFINITY;
        float l1 = v1 ? p1 + __int_as_float(md1.y) : -INFINITY;
        float mn = fmaxf(m, fmaxf(l0, l1));
        float sc = __expf(m - mn);    // finite: m >= -1e30
        float w0 = __expf(l0 - mn);   // 0 for invalid edges
        float w1 = __expf(l1 - mn);
        s  = fmaf(s, sc, w0 + w1);
        ax = fmaf(ax, sc, fmaf(w0, vv0.x, w1 * vv1.x));
        ay = fmaf(ay, sc, fmaf(w0, vv0.y, w1 * vv1.y));
        az = fmaf(az, sc, fmaf(w0, vv0.z, w1 * vv1.z));
        aw = fmaf(aw, sc, fmaf(w0, vv0.w, w1 * vv1.w));
        m = mn;
    }

    // merge the 4 group states
    float m1 = fmaxf(m, __shfl_xor(m, 16));
    float mA = fmaxf(m1, __shfl_xor(m1, 32));
    float scale = __expf(m - mA);
    s *= scale; ax *= scale; ay *= scale; az *= scale; aw *= scale;
    s  += __shfl_xor(s, 16);  s  += __shfl_xor(s, 32);
    ax += __shfl_xor(ax, 16); ax += __shfl_xor(ax, 32);
    ay += __shfl_xor(ay, 16); ay += __shfl_xor(ay, 32);
    az += __shfl_xor(az, 16); az += __shfl_xor(az, 32);
    aw += __shfl_xor(aw, 16); aw += __shfl_xor(aw, 32);

    if (lane < 16) {
        float inv = (end > start) ? 1.0f / s : 0.0f;
        float4 o;
        o.x = ax * inv; o.y = ay * inv; o.z = az * inv; o.w = aw * inv;
        out4[(size_t)b * brow + (size_t)n * 16 + cl] = o;
    }
}

extern "C" void kernel_launch(void* const* d_in, const int* in_sizes, int n_in,
                              void* d_out, int out_size, void* d_ws, size_t ws_size,
                              hipStream_t stream) {
    const float* Q     = (const float*)d_in[0];
    const float* K     = (const float*)d_in[1];
    const float* V     = (const float*)d_in[2];
    const float* efeat = (const float*)d_in[3];
    const float* W1    = (const float*)d_in[4];
    const float* b1    = (const float*)d_in[5];
    const float* W2    = (const float*)d_in[6];
    const float* b2    = (const float*)d_in[7];
    const int*   src   = (const int*)d_in[8];
    const int*   dst   = (const int*)d_in[9];
    float* out = (float*)d_out;

    const int E = in_sizes[8];
    const int N = in_sizes[0] / (EB_B * EB_C);

    // ws layout (ints): offsets[N+1] cnt[N] bsum[64] slot[E] ep[2*E]
    int* offsets = (int*)d_ws;
    int* cnt     = offsets + (N + 1);
    int* bsum    = cnt + N;
    int* slot    = bsum + 64;
    int2* ep     = (int2*)(slot + E);

    hipMemsetAsync(cnt, 0, (size_t)N * sizeof(int), stream);

    int tpb = 256;
    int NB = (N + 1023) >> 10;          // 20 blocks
    eb_count_kernel<<<(E + tpb - 1) / tpb, tpb, 0, stream>>>(dst, cnt, slot, E);
    eb_scan1<<<NB, 1024, 0, stream>>>(cnt, offsets, bsum, N);
    eb_scan2<<<1, 64, 0, stream>>>(bsum, NB);
    eb_scan3<<<(N + 1024) >> 10, 1024, 0, stream>>>(offsets, bsum, N, E);
    eb_fill_kernel<<<(E + tpb - 1) / tpb, tpb, 0, stream>>>(
        dst, src, slot, offsets, efeat, W1, b1, W2, b2, ep, E);

    int tasks = N * EB_B;
    eb_attn_kernel<<<(tasks + 3) / 4, tpb, 0, stream>>>(
        (const float4*)Q, (const float4*)K, (const float4*)V,
        ep, offsets, (float4*)out, N);
}

// Round 7
// 113.431 us; speedup vs baseline: 2.9328x; 1.2475x over previous
//
#include <hip/hip_runtime.h>
#include <hip/hip_fp16.h>
#include <math.h>

// EdgeBiasAttention: B=2, N=20000, C=64, E=640000, H=16
// CSR by dst (atomic-slot + hierarchical scan); ep = int2(src, f32 bias);
// K/V packed to interleaved FP16 rows (uint4 per channel-quad = K-quad +
// V-quad) so each edge-batch costs ONE 16B gather.
// R7 hardening vs R6: (a) all ws sub-buffers 16B-aligned (int2/uint4 were
// misaligned UB), (b) cnt zeroed by a kernel instead of hipMemsetAsync.
// attn: one wave per (node,batch), 4 groups x 16 lanes, 2 edges/group/iter.

#define EB_B 2
#define EB_C 64
#define EB_H 16

__device__ __forceinline__ unsigned f2h2(float a, float b) {
    __half2 h = __floats2half2_rn(a, b);
    return *reinterpret_cast<unsigned*>(&h);
}
__device__ __forceinline__ float2 h2f2(unsigned u) {
    __half2 h = *reinterpret_cast<__half2*>(&u);
    return __half22float2(h);
}

__global__ void eb_zero_kernel(int* __restrict__ p, int n) {
    int i = blockIdx.x * blockDim.x + threadIdx.x;
    if (i < n) p[i] = 0;
}

// Pack K,V (f32) -> interleaved fp16: kv[(b*N+n)*16+cl] = uint4
__global__ __launch_bounds__(256) void eb_pack_kernel(
    const float4* __restrict__ K4, const float4* __restrict__ V4,
    uint4* __restrict__ kv, int total) {
    int i = blockIdx.x * blockDim.x + threadIdx.x;
    if (i >= total) return;
    float4 k = K4[i];
    float4 v = V4[i];
    uint4 o;
    o.x = f2h2(k.x, k.y);
    o.y = f2h2(k.z, k.w);
    o.z = f2h2(v.x, v.y);
    o.w = f2h2(v.z, v.w);
    kv[i] = o;
}

// Pass 1: histogram dst AND remember each edge's slot within its segment.
__global__ void eb_count_kernel(const int* __restrict__ dst,
                                int* __restrict__ cnt,
                                int* __restrict__ slot, int E) {
    int e = blockIdx.x * blockDim.x + threadIdx.x;
    if (e < E) slot[e] = atomicAdd(&cnt[dst[e]], 1);
}

// Scan stage 1: per-block (1024) local exclusive scan + block sums.
__global__ __launch_bounds__(1024) void eb_scan1(const int* __restrict__ cnt,
                                                 int* __restrict__ offsets,
                                                 int* __restrict__ bsum, int N) {
    __shared__ int wsum[16];
    int tid = threadIdx.x;
    int wv = tid >> 6, ln = tid & 63;
    int i = blockIdx.x * 1024 + tid;
    int v = (i < N) ? cnt[i] : 0;
    int x = v;
#pragma unroll
    for (int off = 1; off < 64; off <<= 1) {
        int t = __shfl_up(x, off, 64);
        if (ln >= off) x += t;
    }
    if (ln == 63) wsum[wv] = x;
    __syncthreads();
    if (wv == 0 && ln < 16) {
        int y = wsum[ln];
#pragma unroll
        for (int off = 1; off < 16; off <<= 1) {
            int t = __shfl_up(y, off, 64);
            if (ln >= off) y += t;
        }
        wsum[ln] = y;
    }
    __syncthreads();
    int base = (wv > 0 ? wsum[wv - 1] : 0);
    if (i < N) offsets[i] = base + x - v;
    if (tid == 1023) bsum[blockIdx.x] = base + x;
}

// Scan stage 2: one wave scans the (<=64) block sums -> exclusive bases.
__global__ void eb_scan2(int* __restrict__ bsum, int NB) {
    int ln = threadIdx.x;
    int v = (ln < NB) ? bsum[ln] : 0;
    int x = v;
#pragma unroll
    for (int off = 1; off < 64; off <<= 1) {
        int t = __shfl_up(x, off, 64);
        if (ln >= off) x += t;
    }
    if (ln < NB) bsum[ln] = x - v;
}

// Scan stage 3: add block base; sentinel offsets[N] = E.
__global__ __launch_bounds__(1024) void eb_scan3(int* __restrict__ offsets,
                                                 const int* __restrict__ bsum,
                                                 int N, int E) {
    int i = blockIdx.x * 1024 + threadIdx.x;
    if (i < N) offsets[i] += bsum[blockIdx.x];
    else if (i == N) offsets[N] = E;
}

// Pass 2: atomic-free scatter of int2(src, f32 bias); MLP inline.
__global__ void eb_fill_kernel(const int* __restrict__ dst,
                               const int* __restrict__ src,
                               const int* __restrict__ slot,
                               const int* __restrict__ offsets,
                               const float* __restrict__ efeat,
                               const float* __restrict__ W1,
                               const float* __restrict__ b1,
                               const float* __restrict__ W2,
                               const float* __restrict__ b2,
                               int2* __restrict__ ep, int E) {
    int e = blockIdx.x * blockDim.x + threadIdx.x;
    if (e >= E) return;
    float ef0 = efeat[2 * e];
    float ef1 = efeat[2 * e + 1];
    float acc = b2[0];
#pragma unroll
    for (int h = 0; h < EB_H; ++h) {
        float a = fmaf(ef0, W1[h], fmaf(ef1, W1[EB_H + h], b1[h]));
        a = fmaxf(a, 0.0f);
        acc = fmaf(a, W2[h], acc);
    }
    int pos = offsets[dst[e]] + slot[e];
    ep[pos] = make_int2(src[e], __float_as_int(acc));
}

// fp16 path: one wave per (node,batch); 4 groups x 16 lanes; group g takes
// edges start+it*8+g and +4. One uint4 gather per edge (K-quad + V-quad).
__global__ __launch_bounds__(256) void eb_attn_fp16_kernel(
    const float4* __restrict__ Q4, const uint4* __restrict__ kv,
    const int2* __restrict__ ep, const int* __restrict__ offsets,
    float4* __restrict__ out4, int N) {
    int wave = threadIdx.x >> 6;
    int lane = threadIdx.x & 63;
    int task = blockIdx.x * 4 + wave;
    if (task >= N * EB_B) return;
    int n = task >> 1;
    int b = task & 1;
    int g = lane >> 4;
    int cl = lane & 15;
    const size_t brow = (size_t)N * 16;
    float4 q = Q4[(size_t)b * brow + (size_t)n * 16 + cl];
    const uint4* kvb = kv + (size_t)b * brow;
    int start = offsets[n];
    int end = offsets[n + 1];
    int nit = (end - start + 7) >> 3;

    float m = -1e30f, s = 0.0f;
    float ax = 0.0f, ay = 0.0f, az = 0.0f, aw = 0.0f;

    for (int it = 0; it < nit; ++it) {
        int e0 = start + it * 8 + g;
        int e1 = e0 + 4;
        bool v0 = e0 < end;
        bool v1 = e1 < end;
        int2 md0 = ep[v0 ? e0 : 0];
        int2 md1 = ep[v1 ? e1 : 0];
        uint4 u0 = kvb[(size_t)md0.x * 16 + cl];
        uint4 u1 = kvb[(size_t)md1.x * 16 + cl];
        float2 k0a = h2f2(u0.x), k0b = h2f2(u0.y);
        float2 k1a = h2f2(u1.x), k1b = h2f2(u1.y);
        float p0 = fmaf(q.x, k0a.x, fmaf(q.y, k0a.y,
                   fmaf(q.z, k0b.x, q.w * k0b.y)));
        float p1 = fmaf(q.x, k1a.x, fmaf(q.y, k1a.y,
                   fmaf(q.z, k1b.x, q.w * k1b.y)));
        p0 += __shfl_xor(p0, 1);  p1 += __shfl_xor(p1, 1);
        p0 += __shfl_xor(p0, 2);  p1 += __shfl_xor(p1, 2);
        p0 += __shfl_xor(p0, 4);  p1 += __shfl_xor(p1, 4);
        p0 += __shfl_xor(p0, 8);  p1 += __shfl_xor(p1, 8);
        float l0 = v0 ? p0 + __int_as_float(md0.y) : -INFINITY;
        float l1 = v1 ? p1 + __int_as_float(md1.y) : -INFINITY;
        float mn = fmaxf(m, fmaxf(l0, l1));
        float sc = __expf(m - mn);
        float w0 = __expf(l0 - mn);
        float w1 = __expf(l1 - mn);
        float2 va0 = h2f2(u0.z), vb0 = h2f2(u0.w);
        float2 va1 = h2f2(u1.z), vb1 = h2f2(u1.w);
        s  = fmaf(s, sc, w0 + w1);
        ax = fmaf(ax, sc, fmaf(w0, va0.x, w1 * va1.x));
        ay = fmaf(ay, sc, fmaf(w0, va0.y, w1 * va1.y));
        az = fmaf(az, sc, fmaf(w0, vb0.x, w1 * vb1.x));
        aw = fmaf(aw, sc, fmaf(w0, vb0.y, w1 * vb1.y));
        m = mn;
    }

    float m1 = fmaxf(m, __shfl_xor(m, 16));
    float mA = fmaxf(m1, __shfl_xor(m1, 32));
    float scale = __expf(m - mA);
    s *= scale; ax *= scale; ay *= scale; az *= scale; aw *= scale;
    s  += __shfl_xor(s, 16);  s  += __shfl_xor(s, 32);
    ax += __shfl_xor(ax, 16); ax += __shfl_xor(ax, 32);
    ay += __shfl_xor(ay, 16); ay += __shfl_xor(ay, 32);
    az += __shfl_xor(az, 16); az += __shfl_xor(az, 32);
    aw += __shfl_xor(aw, 16); aw += __shfl_xor(aw, 32);

    if (lane < 16) {
        float inv = (end > start) ? 1.0f / s : 0.0f;
        float4 o;
        o.x = ax * inv; o.y = ay * inv; o.z = az * inv; o.w = aw * inv;
        out4[(size_t)b * brow + (size_t)n * 16 + cl] = o;
    }
}

// f32 fallback (only used if ws_size can't hold the kv copy).
__global__ __launch_bounds__(256) void eb_attn_f32_kernel(
    const float4* __restrict__ Q4, const float4* __restrict__ K4,
    const float4* __restrict__ V4,
    const int2* __restrict__ ep, const int* __restrict__ offsets,
    float4* __restrict__ out4, int N) {
    int wave = threadIdx.x >> 6;
    int lane = threadIdx.x & 63;
    int task = blockIdx.x * 4 + wave;
    if (task >= N * EB_B) return;
    int n = task >> 1;
    int b = task & 1;
    int g = lane >> 4;
    int cl = lane & 15;
    const size_t brow = (size_t)N * 16;
    const float4* Qb = Q4 + (size_t)b * brow;
    const float4* Kb = K4 + (size_t)b * brow;
    const float4* Vb = V4 + (size_t)b * brow;
    float4 q = Qb[(size_t)n * 16 + cl];
    int start = offsets[n];
    int end = offsets[n + 1];
    int nit = (end - start + 3) >> 2;

    float m = -1e30f, s = 0.0f;
    float ax = 0.0f, ay = 0.0f, az = 0.0f, aw = 0.0f;
    for (int it = 0; it < nit; ++it) {
        int ei = start + it * 4 + g;
        bool valid = ei < end;
        int2 md = ep[valid ? ei : 0];
        int sv = md.x;
        float4 k = Kb[(size_t)sv * 16 + cl];
        float4 v = Vb[(size_t)sv * 16 + cl];
        float p = fmaf(q.x, k.x, fmaf(q.y, k.y, fmaf(q.z, k.z, q.w * k.w)));
        p += __shfl_xor(p, 1);
        p += __shfl_xor(p, 2);
        p += __shfl_xor(p, 4);
        p += __shfl_xor(p, 8);
        float l = valid ? p + __int_as_float(md.y) : -INFINITY;
        float mn = fmaxf(m, l);
        float sc = __expf(m - mn);
        float w  = __expf(l - mn);
        s  = fmaf(s, sc, w);
        ax = fmaf(ax, sc, w * v.x);
        ay = fmaf(ay, sc, w * v.y);
        az = fmaf(az, sc, w * v.z);
        aw = fmaf(aw, sc, w * v.w);
        m = mn;
    }
    float m1 = fmaxf(m, __shfl_xor(m, 16));
    float mA = fmaxf(m1, __shfl_xor(m1, 32));
    float scale = __expf(m - mA);
    s *= scale; ax *= scale; ay *= scale; az *= scale; aw *= scale;
    s  += __shfl_xor(s, 16);  s  += __shfl_xor(s, 32);
    ax += __shfl_xor(ax, 16); ax += __shfl_xor(ax, 32);
    ay += __shfl_xor(ay, 16); ay += __shfl_xor(ay, 32);
    az += __shfl_xor(az, 16); az += __shfl_xor(az, 32);
    aw += __shfl_xor(aw, 16); aw += __shfl_xor(aw, 32);
    if (lane < 16) {
        float inv = (end > start) ? 1.0f / s : 0.0f;
        float4 o;
        o.x = ax * inv; o.y = ay * inv; o.z = az * inv; o.w = aw * inv;
        out4[(size_t)b * brow + (size_t)n * 16 + cl] = o;
    }
}

extern "C" void kernel_launch(void* const* d_in, const int* in_sizes, int n_in,
                              void* d_out, int out_size, void* d_ws, size_t ws_size,
                              hipStream_t stream) {
    const float* Q     = (const float*)d_in[0];
    const float* K     = (const float*)d_in[1];
    const float* V     = (const float*)d_in[2];
    const float* efeat = (const float*)d_in[3];
    const float* W1    = (const float*)d_in[4];
    const float* b1    = (const float*)d_in[5];
    const float* W2    = (const float*)d_in[6];
    const float* b2    = (const float*)d_in[7];
    const int*   src   = (const int*)d_in[8];
    const int*   dst   = (const int*)d_in[9];
    float* out = (float*)d_out;

    const int E = in_sizes[8];
    const int N = in_sizes[0] / (EB_B * EB_C);

    // 16B-aligned ws layout (all region starts multiples of 4 ints).
    char* base = (char*)d_ws;
    size_t off = 0;
    auto take = [&](size_t nbytes) {
        char* p = base + off;
        off += (nbytes + 15) & ~(size_t)15;
        return p;
    };
    int* offsets = (int*)take((size_t)(N + 1) * 4);
    int* cnt     = (int*)take((size_t)N * 4);
    int* bsum    = (int*)take(64 * 4);
    int* slot    = (int*)take((size_t)E * 4);
    int2* ep     = (int2*)take((size_t)E * 8);
    size_t base_bytes = off;
    uint4* kv    = (uint4*)take((size_t)EB_B * N * 16 * sizeof(uint4));
    size_t total_bytes = off;
    bool use_fp16 = total_bytes <= ws_size;
    (void)base_bytes;

    int tpb = 256;
    int NB = (N + 1023) >> 10;
    eb_zero_kernel<<<(N + tpb - 1) / tpb, tpb, 0, stream>>>(cnt, N);
    if (use_fp16) {
        int total = EB_B * N * 16;
        eb_pack_kernel<<<(total + tpb - 1) / tpb, tpb, 0, stream>>>(
            (const float4*)K, (const float4*)V, kv, total);
    }
    eb_count_kernel<<<(E + tpb - 1) / tpb, tpb, 0, stream>>>(dst, cnt, slot, E);
    eb_scan1<<<NB, 1024, 0, stream>>>(cnt, offsets, bsum, N);
    eb_scan2<<<1, 64, 0, stream>>>(bsum, NB);
    eb_scan3<<<(N + 1024) >> 10, 1024, 0, stream>>>(offsets, bsum, N, E);
    eb_fill_kernel<<<(E + tpb - 1) / tpb, tpb, 0, stream>>>(
        dst, src, slot, offsets, efeat, W1, b1, W2, b2, ep, E);

    int tasks = N * EB_B;
    if (use_fp16) {
        eb_attn_fp16_kernel<<<(tasks + 3) / 4, tpb, 0, stream>>>(
            (const float4*)Q, kv, ep, offsets, (float4*)out, N);
    } else {
        eb_attn_f32_kernel<<<(tasks + 3) / 4, tpb, 0, stream>>>(
            (const float4*)Q, (const float4*)K, (const float4*)V,
            ep, offsets, (float4*)out, N);
    }
}

// Round 8
// 99.088 us; speedup vs baseline: 3.3573x; 1.1448x over previous
//
#include <hip/hip_runtime.h>
#include <hip/hip_fp16.h>
#include <math.h>

// EdgeBiasAttention: B=2, N=20000, C=64, E=640000, H=16
// CSR by dst (atomic-slot + hierarchical scan); ep = int2(src, f32 bias);
// K/V packed to interleaved FP16 rows (uint4 per channel-quad = K-quad +
// V-quad) so each edge-batch costs ONE 16B gather.
// R8 vs R7: batch-major attn task order (co-resident blocks share one
// batch's 5MB kv in each 4MB XCD L2); cnt zeroing folded into pack;
// scan2 eliminated (scan3 blocks self-sum the <=20 block sums). 6 launches.

#define EB_B 2
#define EB_C 64
#define EB_H 16

__device__ __forceinline__ unsigned f2h2(float a, float b) {
    __half2 h = __floats2half2_rn(a, b);
    return *reinterpret_cast<unsigned*>(&h);
}
__device__ __forceinline__ float2 h2f2(unsigned u) {
    __half2 h = *reinterpret_cast<__half2*>(&u);
    return __half22float2(h);
}

// Pack K,V (f32) -> interleaved fp16 uint4; also zeroes cnt (i < N).
__global__ __launch_bounds__(256) void eb_pack_kernel(
    const float4* __restrict__ K4, const float4* __restrict__ V4,
    uint4* __restrict__ kv, int total, int* __restrict__ cnt, int N) {
    int i = blockIdx.x * blockDim.x + threadIdx.x;
    if (i < N) cnt[i] = 0;
    if (i >= total) return;
    float4 k = K4[i];
    float4 v = V4[i];
    uint4 o;
    o.x = f2h2(k.x, k.y);
    o.y = f2h2(k.z, k.w);
    o.z = f2h2(v.x, v.y);
    o.w = f2h2(v.z, v.w);
    kv[i] = o;
}

// Pass 1: histogram dst AND remember each edge's slot within its segment.
__global__ void eb_count_kernel(const int* __restrict__ dst,
                                int* __restrict__ cnt,
                                int* __restrict__ slot, int E) {
    int e = blockIdx.x * blockDim.x + threadIdx.x;
    if (e < E) slot[e] = atomicAdd(&cnt[dst[e]], 1);
}

// Scan stage 1: per-block (1024) local exclusive scan + block sums.
__global__ __launch_bounds__(1024) void eb_scan1(const int* __restrict__ cnt,
                                                 int* __restrict__ offsets,
                                                 int* __restrict__ bsum, int N) {
    __shared__ int wsum[16];
    int tid = threadIdx.x;
    int wv = tid >> 6, ln = tid & 63;
    int i = blockIdx.x * 1024 + tid;
    int v = (i < N) ? cnt[i] : 0;
    int x = v;
#pragma unroll
    for (int off = 1; off < 64; off <<= 1) {
        int t = __shfl_up(x, off, 64);
        if (ln >= off) x += t;
    }
    if (ln == 63) wsum[wv] = x;
    __syncthreads();
    if (wv == 0 && ln < 16) {
        int y = wsum[ln];
#pragma unroll
        for (int off = 1; off < 16; off <<= 1) {
            int t = __shfl_up(y, off, 64);
            if (ln >= off) y += t;
        }
        wsum[ln] = y;
    }
    __syncthreads();
    int base = (wv > 0 ? wsum[wv - 1] : 0);
    if (i < N) offsets[i] = base + x - v;
    if (tid == 1023) bsum[blockIdx.x] = base + x;
}

// Scan stage 2+3 fused: each block serially sums bsum[0..blockIdx-1]
// (<=20 L2-hot loads), adds to its slice; sentinel offsets[N] = E.
__global__ __launch_bounds__(1024) void eb_scan3(int* __restrict__ offsets,
                                                 const int* __restrict__ bsum,
                                                 int N, int E) {
    __shared__ int s_base;
    if (threadIdx.x == 0) {
        int b = 0;
        for (int j = 0; j < (int)blockIdx.x; ++j) b += bsum[j];
        s_base = b;
    }
    __syncthreads();
    int i = blockIdx.x * 1024 + threadIdx.x;
    if (i < N) offsets[i] += s_base;
    else if (i == N) offsets[N] = E;
}

// Pass 2: atomic-free scatter of int2(src, f32 bias); MLP inline.
__global__ void eb_fill_kernel(const int* __restrict__ dst,
                               const int* __restrict__ src,
                               const int* __restrict__ slot,
                               const int* __restrict__ offsets,
                               const float* __restrict__ efeat,
                               const float* __restrict__ W1,
                               const float* __restrict__ b1,
                               const float* __restrict__ W2,
                               const float* __restrict__ b2,
                               int2* __restrict__ ep, int E) {
    int e = blockIdx.x * blockDim.x + threadIdx.x;
    if (e >= E) return;
    float ef0 = efeat[2 * e];
    float ef1 = efeat[2 * e + 1];
    float acc = b2[0];
#pragma unroll
    for (int h = 0; h < EB_H; ++h) {
        float a = fmaf(ef0, W1[h], fmaf(ef1, W1[EB_H + h], b1[h]));
        a = fmaxf(a, 0.0f);
        acc = fmaf(a, W2[h], acc);
    }
    int pos = offsets[dst[e]] + slot[e];
    ep[pos] = make_int2(src[e], __float_as_int(acc));
}

// fp16 path: one wave per (node,batch), BATCH-MAJOR (task<N -> b=0).
// 4 groups x 16 lanes; group g takes edges start+it*8+g and +4.
__global__ __launch_bounds__(256) void eb_attn_fp16_kernel(
    const float4* __restrict__ Q4, const uint4* __restrict__ kv,
    const int2* __restrict__ ep, const int* __restrict__ offsets,
    float4* __restrict__ out4, int N) {
    int wave = threadIdx.x >> 6;
    int lane = threadIdx.x & 63;
    int task = blockIdx.x * 4 + wave;
    if (task >= N * EB_B) return;
    int b = (task >= N) ? 1 : 0;
    int n = task - (b ? N : 0);
    int g = lane >> 4;
    int cl = lane & 15;
    const size_t brow = (size_t)N * 16;
    float4 q = Q4[(size_t)b * brow + (size_t)n * 16 + cl];
    const uint4* kvb = kv + (size_t)b * brow;
    int start = offsets[n];
    int end = offsets[n + 1];
    int nit = (end - start + 7) >> 3;

    float m = -1e30f, s = 0.0f;
    float ax = 0.0f, ay = 0.0f, az = 0.0f, aw = 0.0f;

    for (int it = 0; it < nit; ++it) {
        int e0 = start + it * 8 + g;
        int e1 = e0 + 4;
        bool v0 = e0 < end;
        bool v1 = e1 < end;
        int2 md0 = ep[v0 ? e0 : 0];
        int2 md1 = ep[v1 ? e1 : 0];
        uint4 u0 = kvb[(size_t)md0.x * 16 + cl];
        uint4 u1 = kvb[(size_t)md1.x * 16 + cl];
        float2 k0a = h2f2(u0.x), k0b = h2f2(u0.y);
        float2 k1a = h2f2(u1.x), k1b = h2f2(u1.y);
        float p0 = fmaf(q.x, k0a.x, fmaf(q.y, k0a.y,
                   fmaf(q.z, k0b.x, q.w * k0b.y)));
        float p1 = fmaf(q.x, k1a.x, fmaf(q.y, k1a.y,
                   fmaf(q.z, k1b.x, q.w * k1b.y)));
        p0 += __shfl_xor(p0, 1);  p1 += __shfl_xor(p1, 1);
        p0 += __shfl_xor(p0, 2);  p1 += __shfl_xor(p1, 2);
        p0 += __shfl_xor(p0, 4);  p1 += __shfl_xor(p1, 4);
        p0 += __shfl_xor(p0, 8);  p1 += __shfl_xor(p1, 8);
        float l0 = v0 ? p0 + __int_as_float(md0.y) : -INFINITY;
        float l1 = v1 ? p1 + __int_as_float(md1.y) : -INFINITY;
        float mn = fmaxf(m, fmaxf(l0, l1));
        float sc = __expf(m - mn);
        float w0 = __expf(l0 - mn);
        float w1 = __expf(l1 - mn);
        float2 va0 = h2f2(u0.z), vb0 = h2f2(u0.w);
        float2 va1 = h2f2(u1.z), vb1 = h2f2(u1.w);
        s  = fmaf(s, sc, w0 + w1);
        ax = fmaf(ax, sc, fmaf(w0, va0.x, w1 * va1.x));
        ay = fmaf(ay, sc, fmaf(w0, va0.y, w1 * va1.y));
        az = fmaf(az, sc, fmaf(w0, vb0.x, w1 * vb1.x));
        aw = fmaf(aw, sc, fmaf(w0, vb0.y, w1 * vb1.y));
        m = mn;
    }

    float m1 = fmaxf(m, __shfl_xor(m, 16));
    float mA = fmaxf(m1, __shfl_xor(m1, 32));
    float scale = __expf(m - mA);
    s *= scale; ax *= scale; ay *= scale; az *= scale; aw *= scale;
    s  += __shfl_xor(s, 16);  s  += __shfl_xor(s, 32);
    ax += __shfl_xor(ax, 16); ax += __shfl_xor(ax, 32);
    ay += __shfl_xor(ay, 16); ay += __shfl_xor(ay, 32);
    az += __shfl_xor(az, 16); az += __shfl_xor(az, 32);
    aw += __shfl_xor(aw, 16); aw += __shfl_xor(aw, 32);

    if (lane < 16) {
        float inv = (end > start) ? 1.0f / s : 0.0f;
        float4 o;
        o.x = ax * inv; o.y = ay * inv; o.z = az * inv; o.w = aw * inv;
        out4[(size_t)b * brow + (size_t)n * 16 + cl] = o;
    }
}

// f32 fallback (only used if ws_size can't hold the kv copy).
__global__ __launch_bounds__(256) void eb_attn_f32_kernel(
    const float4* __restrict__ Q4, const float4* __restrict__ K4,
    const float4* __restrict__ V4,
    const int2* __restrict__ ep, const int* __restrict__ offsets,
    float4* __restrict__ out4, int N) {
    int wave = threadIdx.x >> 6;
    int lane = threadIdx.x & 63;
    int task = blockIdx.x * 4 + wave;
    if (task >= N * EB_B) return;
    int b = (task >= N) ? 1 : 0;
    int n = task - (b ? N : 0);
    int g = lane >> 4;
    int cl = lane & 15;
    const size_t brow = (size_t)N * 16;
    const float4* Qb = Q4 + (size_t)b * brow;
    const float4* Kb = K4 + (size_t)b * brow;
    const float4* Vb = V4 + (size_t)b * brow;
    float4 q = Qb[(size_t)n * 16 + cl];
    int start = offsets[n];
    int end = offsets[n + 1];
    int nit = (end - start + 3) >> 2;

    float m = -1e30f, s = 0.0f;
    float ax = 0.0f, ay = 0.0f, az = 0.0f, aw = 0.0f;
    for (int it = 0; it < nit; ++it) {
        int ei = start + it * 4 + g;
        bool valid = ei < end;
        int2 md = ep[valid ? ei : 0];
        int sv = md.x;
        float4 k = Kb[(size_t)sv * 16 + cl];
        float4 v = Vb[(size_t)sv * 16 + cl];
        float p = fmaf(q.x, k.x, fmaf(q.y, k.y, fmaf(q.z, k.z, q.w * k.w)));
        p += __shfl_xor(p, 1);
        p += __shfl_xor(p, 2);
        p += __shfl_xor(p, 4);
        p += __shfl_xor(p, 8);
        float l = valid ? p + __int_as_float(md.y) : -INFINITY;
        float mn = fmaxf(m, l);
        float sc = __expf(m - mn);
        float w  = __expf(l - mn);
        s  = fmaf(s, sc, w);
        ax = fmaf(ax, sc, w * v.x);
        ay = fmaf(ay, sc, w * v.y);
        az = fmaf(az, sc, w * v.z);
        aw = fmaf(aw, sc, w * v.w);
        m = mn;
    }
    float m1 = fmaxf(m, __shfl_xor(m, 16));
    float mA = fmaxf(m1, __shfl_xor(m1, 32));
    float scale = __expf(m - mA);
    s *= scale; ax *= scale; ay *= scale; az *= scale; aw *= scale;
    s  += __shfl_xor(s, 16);  s  += __shfl_xor(s, 32);
    ax += __shfl_xor(ax, 16); ax += __shfl_xor(ax, 32);
    ay += __shfl_xor(ay, 16); ay += __shfl_xor(ay, 32);
    az += __shfl_xor(az, 16); az += __shfl_xor(az, 32);
    aw += __shfl_xor(aw, 16); aw += __shfl_xor(aw, 32);
    if (lane < 16) {
        float inv = (end > start) ? 1.0f / s : 0.0f;
        float4 o;
        o.x = ax * inv; o.y = ay * inv; o.z = az * inv; o.w = aw * inv;
        out4[(size_t)b * brow + (size_t)n * 16 + cl] = o;
    }
}

extern "C" void kernel_launch(void* const* d_in, const int* in_sizes, int n_in,
                              void* d_out, int out_size, void* d_ws, size_t ws_size,
                              hipStream_t stream) {
    const float* Q     = (const float*)d_in[0];
    const float* K     = (const float*)d_in[1];
    const float* V     = (const float*)d_in[2];
    const float* efeat = (const float*)d_in[3];
    const float* W1    = (const float*)d_in[4];
    const float* b1    = (const float*)d_in[5];
    const float* W2    = (const float*)d_in[6];
    const float* b2    = (const float*)d_in[7];
    const int*   src   = (const int*)d_in[8];
    const int*   dst   = (const int*)d_in[9];
    float* out = (float*)d_out;

    const int E = in_sizes[8];
    const int N = in_sizes[0] / (EB_B * EB_C);

    // 16B-aligned ws layout.
    char* base = (char*)d_ws;
    size_t off = 0;
    auto take = [&](size_t nbytes) {
        char* p = base + off;
        off += (nbytes + 15) & ~(size_t)15;
        return p;
    };
    int* offsets = (int*)take((size_t)(N + 1) * 4);
    int* cnt     = (int*)take((size_t)N * 4);
    int* bsum    = (int*)take(64 * 4);
    int* slot    = (int*)take((size_t)E * 4);
    int2* ep     = (int2*)take((size_t)E * 8);
    uint4* kv    = (uint4*)take((size_t)EB_B * N * 16 * sizeof(uint4));
    bool use_fp16 = off <= ws_size;

    int tpb = 256;
    int NB = (N + 1023) >> 10;
    if (use_fp16) {
        int total = EB_B * N * 16;
        eb_pack_kernel<<<(total + tpb - 1) / tpb, tpb, 0, stream>>>(
            (const float4*)K, (const float4*)V, kv, total, cnt, N);
    } else {
        eb_pack_kernel<<<(N + tpb - 1) / tpb, tpb, 0, stream>>>(
            (const float4*)K, (const float4*)V, kv, 0, cnt, N);
    }
    eb_count_kernel<<<(E + tpb - 1) / tpb, tpb, 0, stream>>>(dst, cnt, slot, E);
    eb_scan1<<<NB, 1024, 0, stream>>>(cnt, offsets, bsum, N);
    eb_scan3<<<(N + 1024) >> 10, 1024, 0, stream>>>(offsets, bsum, N, E);
    eb_fill_kernel<<<(E + tpb - 1) / tpb, tpb, 0, stream>>>(
        dst, src, slot, offsets, efeat, W1, b1, W2, b2, ep, E);

    int tasks = N * EB_B;
    if (use_fp16) {
        eb_attn_fp16_kernel<<<(tasks + 3) / 4, tpb, 0, stream>>>(
            (const float4*)Q, kv, ep, offsets, (float4*)out, N);
    } else {
        eb_attn_f32_kernel<<<(tasks + 3) / 4, tpb, 0, stream>>>(
            (const float4*)Q, (const float4*)K, (const float4*)V,
            ep, offsets, (float4*)out, N);
    }
}